// Round 1
// baseline (2292.814 us; speedup 1.0000x reference)
//
#include <hip/hip_runtime.h>

#define NN 100000
#define NE 1600000
#define XDIM 136
#define XPAD 144
#define LAM 0.05f
#define GAMMAF 1.0f

// ---------------- Kernel 1: V = H @ W_v^T, T = H @ W_t^T (fused) ----------------
__global__ __launch_bounds__(256) void k1_vt(
    const float* __restrict__ H, const float* __restrict__ Wv,
    const float* __restrict__ Wt, float* __restrict__ V, float* __restrict__ T)
{
  __shared__ float Wc[128*129];   // rows 0..63 = W_v, 64..127 = W_t, padded stride 129
  __shared__ float Hl[256];
  const int tid = threadIdx.x;
  for (int i = tid; i < 128*128; i += 256) {
    int r = i >> 7, k = i & 127;
    Wc[r*129 + k] = (r < 64) ? Wv[r*128 + k] : Wt[(r-64)*128 + k];
  }
  __syncthreads();
  const int c = tid & 127;
  const int sub = tid >> 7;
  for (int pair = blockIdx.x; pair*2 < NN; pair += gridDim.x) {
    const int nbase = pair*2;
    Hl[tid] = H[nbase*128 + tid];           // 2 rows staged, coalesced
    __syncthreads();
    const float* hh = &Hl[sub*128];
    const float* wr = &Wc[c*129];
    float a0=0.f,a1=0.f,a2=0.f,a3=0.f;
    #pragma unroll
    for (int k = 0; k < 128; k += 4) {
      a0 = fmaf(hh[k],   wr[k],   a0);
      a1 = fmaf(hh[k+1], wr[k+1], a1);
      a2 = fmaf(hh[k+2], wr[k+2], a2);
      a3 = fmaf(hh[k+3], wr[k+3], a3);
    }
    const float acc = (a0+a1)+(a2+a3);
    const int n = nbase + sub;
    if (c < 64) V[n*64 + c] = acc; else T[n*64 + (c-64)] = acc;
    __syncthreads();
  }
}

// ---------------- Kernel 2: edge MLP + softshrink + loss + signed scatter ----------------
__global__ __launch_bounds__(512) void k2_edge(
    const float* __restrict__ V, const float* __restrict__ T,
    const float* __restrict__ semb, const float* __restrict__ w1,
    const float* __restrict__ b1, const float* __restrict__ w2,
    const float* __restrict__ b2, const int* __restrict__ eidx,
    const int* __restrict__ esign, float* __restrict__ agg,
    float* __restrict__ loss)
{
  __shared__ float wT[XDIM*128];      // wT[k*128 + r] = mlp1_w[r][k]  (69.6 KB)
  __shared__ float xs[8][8][XPAD];    // [wave][edge][x]               (36.9 KB)
  const int tid = threadIdx.x;
  for (int i = tid; i < 128*XDIM; i += 512) {
    int r = i / XDIM, k = i - r*XDIM;
    wT[k*128 + r] = w1[i];
  }
  __syncthreads();
  const int wid = tid >> 6, l = tid & 63;
  float (*xw)[XPAD] = xs[wid];
  const float bb0 = b1[l],  bb1 = b1[64+l];
  const float ww0 = w2[l],  ww1 = w2[64+l];
  const float bb2 = b2[0];
  float loss_acc = 0.f;
  const int ngroups = (NE + 7) >> 3;
  for (int g = blockIdx.x*8 + wid; g < ngroups; g += gridDim.x*8) {
    int cols[8]; int sgns[8];
    #pragma unroll
    for (int e = 0; e < 8; ++e) {
      const int eid = g*8 + e;
      if (eid < NE) {
        const int row = eidx[eid];
        const int col = eidx[NE + eid];
        const int sg  = esign[eid];
        cols[e] = col; sgns[e] = sg;
        xw[e][l]      = T[col*64 + l];
        xw[e][64 + l] = V[row*64 + l];
        if (l < 8) xw[e][128 + l] = semb[(sg+1)*8 + l];
      } else { cols[e] = -1; sgns[e] = 0; }
    }
    float acc0[8] = {0,0,0,0,0,0,0,0};
    float acc1[8] = {0,0,0,0,0,0,0,0};
    for (int k = 0; k < XDIM; ++k) {
      const float w0  = wT[k*128 + l];        // conflict-free (2 lanes/bank)
      const float w1v = wT[k*128 + 64 + l];
      #pragma unroll
      for (int e = 0; e < 8; ++e) {
        const float xe = xw[e][k];            // wave-uniform broadcast
        acc0[e] = fmaf(w0,  xe, acc0[e]);
        acc1[e] = fmaf(w1v, xe, acc1[e]);
      }
    }
    #pragma unroll
    for (int e = 0; e < 8; ++e) {
      if (cols[e] < 0) continue;
      float c0 = acc0[e] + bb0; c0 = c0 > 0.f ? c0 : 0.f;
      float c1 = acc1[e] + bb1; c1 = c1 > 0.f ? c1 : 0.f;
      float contrib = fmaf(c0, ww0, c1*ww1);
      #pragma unroll
      for (int off = 32; off > 0; off >>= 1)
        contrib += __shfl_xor(contrib, off, 64);
      const float alpha = contrib + bb2;
      const float sa = (alpha > LAM) ? (alpha - LAM)
                     : ((alpha < -LAM) ? (alpha + LAM) : 0.f);
      loss_acc += fabsf(sa);
      const int sg = sgns[e];
      if (sg != 0 && sa != 0.f) {
        const float we = (sg > 0) ? sa : -GAMMAF*fabsf(sa);
        atomicAdd(&agg[cols[e]*64 + l], we * xw[e][64 + l]);
      }
    }
  }
  if (l == 0) atomicAdd(loss, loss_acc);
}

// ---------------- Kernel 3: out = agg @ W_out^T + b + H @ W_self^T + H; loss write ----------------
__global__ __launch_bounds__(256) void k3_out(
    const float* __restrict__ H, const float* __restrict__ agg,
    const float* __restrict__ Wself, const float* __restrict__ Wout,
    const float* __restrict__ Wob, const float* __restrict__ loss,
    float* __restrict__ out)
{
  __shared__ float Ws[128*129];   // 66.0 KB
  __shared__ float Wo[128*65];    // 33.3 KB
  __shared__ float Hl[256];
  __shared__ float Al[128];
  const int tid = threadIdx.x;
  for (int i = tid; i < 128*128; i += 256) { int r=i>>7,k=i&127; Ws[r*129+k]=Wself[i]; }
  for (int i = tid; i < 128*64;  i += 256) { int r=i>>6,k=i&63;  Wo[r*65+k]=Wout[i]; }
  __syncthreads();
  const int c = tid & 127, sub = tid >> 7;
  const float bc = Wob[c];
  for (int pair = blockIdx.x; pair*2 < NN; pair += gridDim.x) {
    const int nbase = pair*2;
    Hl[tid] = H[nbase*128 + tid];
    if (tid < 128) Al[tid] = agg[nbase*64 + tid];
    __syncthreads();
    const float* hh = &Hl[sub*128];
    const float* aa = &Al[sub*64];
    const float* wr = &Ws[c*129];
    const float* wo = &Wo[c*65];
    float a0=0.f,a1=0.f,a2=0.f,a3=0.f;
    #pragma unroll
    for (int k = 0; k < 128; k += 4) {
      a0 = fmaf(hh[k],   wr[k],   a0);
      a1 = fmaf(hh[k+1], wr[k+1], a1);
      a2 = fmaf(hh[k+2], wr[k+2], a2);
      a3 = fmaf(hh[k+3], wr[k+3], a3);
    }
    #pragma unroll
    for (int k = 0; k < 64; k += 4) {
      a0 = fmaf(aa[k],   wo[k],   a0);
      a1 = fmaf(aa[k+1], wo[k+1], a1);
      a2 = fmaf(aa[k+2], wo[k+2], a2);
      a3 = fmaf(aa[k+3], wo[k+3], a3);
    }
    const int n = nbase + sub;
    out[n*128 + c] = bc + Hl[sub*128 + c] + (a0+a1)+(a2+a3);
    __syncthreads();
  }
  if (blockIdx.x == 0 && tid == 0) out[12800000] = (*loss) * (1.0f/NE);
}

extern "C" void kernel_launch(void* const* d_in, const int* in_sizes, int n_in,
                              void* d_out, int out_size, void* d_ws, size_t ws_size,
                              hipStream_t stream) {
  const float* H     = (const float*)d_in[0];
  const float* Wv    = (const float*)d_in[1];
  const float* Wt    = (const float*)d_in[2];
  const float* semb  = (const float*)d_in[3];
  const float* w1    = (const float*)d_in[4];
  const float* b1    = (const float*)d_in[5];
  const float* w2    = (const float*)d_in[6];
  const float* b2    = (const float*)d_in[7];
  const float* Wself = (const float*)d_in[8];
  const float* Wout  = (const float*)d_in[9];
  const float* Wob   = (const float*)d_in[10];
  const int*   eidx  = (const int*)d_in[11];
  const int*   esign = (const int*)d_in[12];
  float* out = (float*)d_out;

  // ws layout: agg [100000*64 f32] then loss [1 f32]
  float* agg  = (float*)d_ws;
  float* loss = (float*)((char*)d_ws + 25600000);
  // V/T live in d_out temporarily (12.8M floats needed, out has 12,800,001);
  // kernel 3 overwrites every element afterwards.
  float* V = out;
  float* T = out + 6400000;

  hipMemsetAsync(d_ws, 0, 25600004, stream);   // zero agg + loss
  k1_vt  <<<2048, 256, 0, stream>>>(H, Wv, Wt, V, T);
  k2_edge<<<1024, 512, 0, stream>>>(V, T, semb, w1, b1, w2, b2, eidx, esign, agg, loss);
  k3_out <<<2048, 256, 0, stream>>>(H, agg, Wself, Wout, Wob, loss, out);
}

// Round 3
// 475.804 us; speedup vs baseline: 4.8188x; 4.8188x over previous
//
#include <hip/hip_runtime.h>

#define NN 100000
#define NE 1600000
#define LAM 0.05f

typedef __attribute__((ext_vector_type(8))) short bf16x8;
typedef __attribute__((ext_vector_type(8))) unsigned short u16x8;
typedef __attribute__((ext_vector_type(4))) float f32x4;

__device__ inline unsigned short f2bf(float x) {
  unsigned u = __builtin_bit_cast(unsigned, x);
  u = (u + 0x7FFFu + ((u >> 16) & 1u)) >> 16;
  return (unsigned short)u;
}
__device__ inline float bf2f(unsigned short h) {
  unsigned u = ((unsigned)h) << 16;
  return __builtin_bit_cast(float, u);
}
__device__ inline u16x8 pack2(float4 a, float4 b) {
  u16x8 p;
  p[0]=f2bf(a.x); p[1]=f2bf(a.y); p[2]=f2bf(a.z); p[3]=f2bf(a.w);
  p[4]=f2bf(b.x); p[5]=f2bf(b.y); p[6]=f2bf(b.z); p[7]=f2bf(b.w);
  return p;
}
__device__ inline u16x8 zero8() {
  u16x8 z;
  #pragma unroll
  for (int i = 0; i < 8; ++i) z[i] = 0;
  return z;
}
__device__ inline f32x4 zero4() {
  f32x4 z;
  z[0] = z[1] = z[2] = z[3] = 0.f;
  return z;
}

#define MFMA(a,b,c) __builtin_amdgcn_mfma_f32_16x16x32_bf16((bf16x8)(a),(bf16x8)(b),(c),0,0,0)

// ============ Kernel 1: V|T = H @ [Wv|Wt]^T via MFMA ============
#define K1S 136
__global__ __launch_bounds__(256) void k1_vt(
    const float* __restrict__ H, const float* __restrict__ Wv,
    const float* __restrict__ Wt, float* __restrict__ V, float* __restrict__ T)
{
  __shared__ unsigned short Wl[128*K1S];  // [col 0..63=V,64..127=T][k] bf16
  __shared__ unsigned short Hs[64*K1S];   // [row][k] bf16
  const int tid = threadIdx.x;
  for (int idx = tid; idx < 128*16; idx += 256) {   // 8-float segments
    int c = idx >> 4, k = (idx & 15) * 8;
    const float* src = (c < 64) ? (Wv + c*128 + k) : (Wt + (c-64)*128 + k);
    *(u16x8*)&Wl[c*K1S + k] = pack2(*(const float4*)src, *(const float4*)(src+4));
  }
  __syncthreads();
  const int wv = tid >> 6, l = tid & 63, l15 = l & 15, lh = l >> 4;
  const int ntiles = (NN + 63) >> 6;
  for (int t = blockIdx.x; t < ntiles; t += gridDim.x) {
    const int nb = t * 64;
    {
      const int r = tid >> 2, q = tid & 3, row = nb + r;
      if (row < NN) {
        const float* src = H + row*128 + q*32;
        #pragma unroll
        for (int s = 0; s < 4; ++s)
          *(u16x8*)&Hs[r*K1S + q*32 + s*8] =
              pack2(*(const float4*)(src + s*8), *(const float4*)(src + s*8 + 4));
      } else {
        #pragma unroll
        for (int s = 0; s < 4; ++s) *(u16x8*)&Hs[r*K1S + q*32 + s*8] = zero8();
      }
    }
    __syncthreads();
    f32x4 acc[4][2];
    #pragma unroll
    for (int m = 0; m < 4; ++m) { acc[m][0] = zero4(); acc[m][1] = zero4(); }
    #pragma unroll
    for (int kk = 0; kk < 128; kk += 32) {
      const int kb = kk + lh*8;
      bf16x8 bf0 = *(const bf16x8*)&Wl[(wv*32 + l15)*K1S + kb];
      bf16x8 bf1 = *(const bf16x8*)&Wl[(wv*32 + 16 + l15)*K1S + kb];
      #pragma unroll
      for (int m = 0; m < 4; ++m) {
        bf16x8 af = *(const bf16x8*)&Hs[(m*16 + l15)*K1S + kb];
        acc[m][0] = MFMA(af, bf0, acc[m][0]);
        acc[m][1] = MFMA(af, bf1, acc[m][1]);
      }
    }
    #pragma unroll
    for (int m = 0; m < 4; ++m) {
      const int rowl = m*16 + lh*4;
      #pragma unroll
      for (int n = 0; n < 2; ++n) {
        const int col = wv*32 + n*16 + l15;
        #pragma unroll
        for (int r = 0; r < 4; ++r) {
          const int node = nb + rowl + r;
          if (node < NN) {
            if (col < 64) V[node*64 + col] = acc[m][n][r];
            else          T[node*64 + col - 64] = acc[m][n][r];
          }
        }
      }
    }
    __syncthreads();
  }
}

// ============ Kernel 2: edge MLP (MFMA) + softshrink + loss + scatter ============
#define XS 168   // LDS row stride (bf16) for K padded to 160
__global__ __launch_bounds__(256) void k2_edge(
    const float* __restrict__ V, const float* __restrict__ T,
    const float* __restrict__ semb, const float* __restrict__ w1,
    const float* __restrict__ b1, const float* __restrict__ w2,
    const float* __restrict__ b2, const int* __restrict__ eidx,
    const int* __restrict__ esign, float* __restrict__ agg,
    float* __restrict__ loss)
{
  __shared__ unsigned short Wl[128*XS];   // w1 [hid][k] bf16, k 136..168 zero
  __shared__ unsigned short X[64*XS];     // [edge][t_i(64)|v_j(64)|semb(8)|0...]
  __shared__ float apart[4*64];
  __shared__ float weS[64];
  __shared__ int colS[64];
  __shared__ int sgnS[64];
  const int tid = threadIdx.x;
  for (int idx = tid; idx < 128*17; idx += 256) {
    int c = idx / 17, k = (idx % 17) * 8;
    const float* src = w1 + c*136 + k;
    *(u16x8*)&Wl[c*XS + k] = pack2(*(const float4*)src, *(const float4*)(src+4));
  }
  for (int idx = tid; idx < 128*4; idx += 256) {  // zero w1 pad k=136..168
    int c = idx >> 2, s = idx & 3;
    *(u16x8*)&Wl[c*XS + 136 + s*8] = zero8();
  }
  for (int idx = tid; idx < 64*4; idx += 256) {   // zero X pad cols 136..168 (persistent)
    int r = idx >> 2, s = idx & 3;
    *(u16x8*)&X[r*XS + 136 + s*8] = zero8();
  }
  const int wv = tid >> 6, l = tid & 63, l15 = l & 15, lh = l >> 4;
  const float b1v0 = b1[wv*32 + l15],      b1v1 = b1[wv*32 + 16 + l15];
  const float w2v0 = w2[wv*32 + l15],      w2v1 = w2[wv*32 + 16 + l15];
  const float b2v = b2[0];
  float loss_acc = 0.f;
  __syncthreads();
  for (int t = blockIdx.x; t < NE/64; t += gridDim.x) {
    const int eb = t * 64;
    {
      const int e = tid >> 2, q = tid & 3, eid = eb + e;
      const int row = eidx[eid], co = eidx[NE + eid], sg = esign[eid];
      const float* tp = T + co*64 + q*16;
      const float* vp = V + row*64 + q*16;
      #pragma unroll
      for (int s = 0; s < 2; ++s) {
        *(u16x8*)&X[e*XS + q*16 + s*8] =
            pack2(*(const float4*)(tp + s*8), *(const float4*)(tp + s*8 + 4));
        *(u16x8*)&X[e*XS + 64 + q*16 + s*8] =
            pack2(*(const float4*)(vp + s*8), *(const float4*)(vp + s*8 + 4));
      }
      if (q == 0) {
        const float* sp = semb + (sg + 1) * 8;
        *(u16x8*)&X[e*XS + 128] = pack2(*(const float4*)sp, *(const float4*)(sp+4));
        colS[e] = co; sgnS[e] = sg;
      }
    }
    __syncthreads();
    f32x4 acc[4][2];
    #pragma unroll
    for (int m = 0; m < 4; ++m) { acc[m][0] = zero4(); acc[m][1] = zero4(); }
    #pragma unroll
    for (int kk = 0; kk < 160; kk += 32) {
      const int kb = kk + lh*8;
      bf16x8 bf0 = *(const bf16x8*)&Wl[(wv*32 + l15)*XS + kb];
      bf16x8 bf1 = *(const bf16x8*)&Wl[(wv*32 + 16 + l15)*XS + kb];
      #pragma unroll
      for (int m = 0; m < 4; ++m) {
        bf16x8 af = *(const bf16x8*)&X[(m*16 + l15)*XS + kb];
        acc[m][0] = MFMA(af, bf0, acc[m][0]);
        acc[m][1] = MFMA(af, bf1, acc[m][1]);
      }
    }
    // relu + dot with w2 (this wave's 32 hid cols) + reduce over 16 lanes
    #pragma unroll
    for (int m = 0; m < 4; ++m) {
      f32x4 s;
      #pragma unroll
      for (int r = 0; r < 4; ++r) {
        float h0 = acc[m][0][r] + b1v0; h0 = h0 > 0.f ? h0 : 0.f;
        float h1 = acc[m][1][r] + b1v1; h1 = h1 > 0.f ? h1 : 0.f;
        s[r] = fmaf(h0, w2v0, h1 * w2v1);
      }
      #pragma unroll
      for (int off = 1; off < 16; off <<= 1) {
        s[0] += __shfl_xor(s[0], off, 64);
        s[1] += __shfl_xor(s[1], off, 64);
        s[2] += __shfl_xor(s[2], off, 64);
        s[3] += __shfl_xor(s[3], off, 64);
      }
      if (l15 == 0) *(f32x4*)&apart[wv*64 + m*16 + lh*4] = s;
    }
    __syncthreads();
    if (wv == 0) {
      float alpha = apart[l] + apart[64+l] + apart[128+l] + apart[192+l] + b2v;
      float sa = (alpha > LAM) ? (alpha - LAM)
               : ((alpha < -LAM) ? (alpha + LAM) : 0.f);
      loss_acc += fabsf(sa);
      const int sg = sgnS[l];
      weS[l] = (sg > 0) ? sa : ((sg < 0) ? -fabsf(sa) : 0.f);
    }
    __syncthreads();
    #pragma unroll 4
    for (int i = 0; i < 16; ++i) {
      const int e = wv*16 + i;
      const float we = weS[e];
      if (we != 0.f) {
        const float vj = bf2f(X[e*XS + 64 + l]);
        atomicAdd(&agg[colS[e]*64 + l], we * vj);
      }
    }
    __syncthreads();
  }
  if (wv == 0) {
    #pragma unroll
    for (int off = 1; off < 64; off <<= 1) loss_acc += __shfl_xor(loss_acc, off, 64);
    if (l == 0) atomicAdd(loss, loss_acc);
  }
}

// ============ Kernel 3: out = [H|agg] @ [Wself|Wout]^T + b + H (MFMA) ============
#define K3S 200
__global__ __launch_bounds__(256) void k3_out(
    const float* __restrict__ H, const float* __restrict__ agg,
    const float* __restrict__ Wself, const float* __restrict__ Wout,
    const float* __restrict__ Wob, const float* __restrict__ loss,
    float* __restrict__ out)
{
  __shared__ unsigned short Wl[128*K3S];  // [col][k: 0..128 Wself | 128..192 Wout]
  __shared__ unsigned short Hs[64*K3S];   // [row][k: H | agg]
  const int tid = threadIdx.x;
  for (int idx = tid; idx < 128*24; idx += 256) {
    int c = idx / 24, k = (idx % 24) * 8;
    const float* src = (k < 128) ? (Wself + c*128 + k) : (Wout + c*64 + (k-128));
    *(u16x8*)&Wl[c*K3S + k] = pack2(*(const float4*)src, *(const float4*)(src+4));
  }
  __syncthreads();
  const int wv = tid >> 6, l = tid & 63, l15 = l & 15, lh = l >> 4;
  const float wob0 = Wob[wv*32 + l15], wob1 = Wob[wv*32 + 16 + l15];
  const int ntiles = (NN + 63) >> 6;
  for (int t = blockIdx.x; t < ntiles; t += gridDim.x) {
    const int nb = t * 64;
    {
      const int r = tid >> 2, q = tid & 3, row = nb + r;
      if (row < NN) {
        const float* hsrc = H + row*128 + q*32;
        #pragma unroll
        for (int s = 0; s < 4; ++s)
          *(u16x8*)&Hs[r*K3S + q*32 + s*8] =
              pack2(*(const float4*)(hsrc + s*8), *(const float4*)(hsrc + s*8 + 4));
        const float* asrc = agg + row*64 + q*16;
        #pragma unroll
        for (int s = 0; s < 2; ++s)
          *(u16x8*)&Hs[r*K3S + 128 + q*16 + s*8] =
              pack2(*(const float4*)(asrc + s*8), *(const float4*)(asrc + s*8 + 4));
      } else {
        #pragma unroll
        for (int s = 0; s < 4; ++s) *(u16x8*)&Hs[r*K3S + q*32 + s*8] = zero8();
        #pragma unroll
        for (int s = 0; s < 2; ++s) *(u16x8*)&Hs[r*K3S + 128 + q*16 + s*8] = zero8();
      }
    }
    __syncthreads();
    f32x4 acc[4][2];
    #pragma unroll
    for (int m = 0; m < 4; ++m) { acc[m][0] = zero4(); acc[m][1] = zero4(); }
    #pragma unroll
    for (int kk = 0; kk < 192; kk += 32) {
      const int kb = kk + lh*8;
      bf16x8 bf0 = *(const bf16x8*)&Wl[(wv*32 + l15)*K3S + kb];
      bf16x8 bf1 = *(const bf16x8*)&Wl[(wv*32 + 16 + l15)*K3S + kb];
      #pragma unroll
      for (int m = 0; m < 4; ++m) {
        bf16x8 af = *(const bf16x8*)&Hs[(m*16 + l15)*K3S + kb];
        acc[m][0] = MFMA(af, bf0, acc[m][0]);
        acc[m][1] = MFMA(af, bf1, acc[m][1]);
      }
    }
    #pragma unroll
    for (int m = 0; m < 4; ++m) {
      const int rowl = m*16 + lh*4;
      #pragma unroll
      for (int n = 0; n < 2; ++n) {
        const int col = wv*32 + n*16 + l15;
        const float wob = n ? wob1 : wob0;
        #pragma unroll
        for (int r = 0; r < 4; ++r) {
          const int node = nb + rowl + r;
          if (node < NN)
            out[node*128 + col] = acc[m][n][r] + wob + H[node*128 + col];
        }
      }
    }
    __syncthreads();
  }
  if (blockIdx.x == 0 && tid == 0) out[NN*128] = loss[0] * (1.0f / NE);
}

extern "C" void kernel_launch(void* const* d_in, const int* in_sizes, int n_in,
                              void* d_out, int out_size, void* d_ws, size_t ws_size,
                              hipStream_t stream) {
  const float* H     = (const float*)d_in[0];
  const float* Wv    = (const float*)d_in[1];
  const float* Wt    = (const float*)d_in[2];
  const float* semb  = (const float*)d_in[3];
  const float* w1    = (const float*)d_in[4];
  const float* b1    = (const float*)d_in[5];
  const float* w2    = (const float*)d_in[6];
  const float* b2    = (const float*)d_in[7];
  const float* Wself = (const float*)d_in[8];
  const float* Wout  = (const float*)d_in[9];
  const float* Wob   = (const float*)d_in[10];
  const int*   eidx  = (const int*)d_in[11];
  const int*   esign = (const int*)d_in[12];
  float* out = (float*)d_out;

  float* agg  = (float*)d_ws;                       // 100000*64 f32
  float* loss = (float*)((char*)d_ws + 25600000);   // 1 f32
  float* V = out;                                   // scratch in d_out, overwritten by k3
  float* T = out + 6400000;

  (void)hipMemsetAsync(d_ws, 0, 25600004, stream);
  k1_vt  <<<768, 256, 0, stream>>>(H, Wv, Wt, V, T);
  k2_edge<<<512, 256, 0, stream>>>(V, T, semb, w1, b1, w2, b2, eidx, esign, agg, loss);
  k3_out <<<512, 256, 0, stream>>>(H, agg, Wself, Wout, Wob, loss, out);
}